// Round 9
// baseline (235.913 us; speedup 1.0000x reference)
//
#include <hip/hip_runtime.h>
#include <math.h>

#define D_IN   1024
#define STACKN 4
#define BATCHN 8192
#define OUTW   (STACKN * D_IN)   // 4096
#define REPS   3                 // DIAGNOSTIC: x3 work so whvi_main tops the rocprof table

typedef int   iv2 __attribute__((ext_vector_type(2)));
typedef float fv4 __attribute__((ext_vector_type(4)));

__device__ __forceinline__ int   f2i(float x){ union{float f;int i;}u; u.f=x; return u.i; }
__device__ __forceinline__ float i2f(int x){ union{float f;int i;}u; u.i=x; return u.f; }

// DPP move: dst lane gets src lane per CTRL (quad_perm / row_ror), full masks.
template<int CTRL>
__device__ __forceinline__ float dpp_mov(float v){
    return i2f(__builtin_amdgcn_update_dpp(0, f2i(v), CTRL, 0xF, 0xF, false));
}

// Unnormalized FWHT-1024 over one wave (R2-proven mix).
// element i = k*256 + lane*4 + c ; reg r = k*4 + c.
// i-bits: [1:0]=c (reg masks 1,2) [7:2]=lane [9:8]=k (reg masks 4,8).
__device__ __forceinline__ void fwht1024(float v[16],
                                         float sg1, float sg2,
                                         float sg4, float sg8)
{
    // ---- register-local stages (i-bits 0,1,8,9) ----
    #pragma unroll
    for (int m = 1; m <= 8; m <<= 1) {
        #pragma unroll
        for (int r = 0; r < 16; ++r) {
            if (!(r & m)) {
                float a = v[r], b = v[r ^ m];
                v[r]     = a + b;
                v[r ^ m] = a - b;
            }
        }
    }
    // ---- lane xor 1: DPP quad_perm [1,0,3,2] ----
    #pragma unroll
    for (int r = 0; r < 16; ++r) {
        float t = dpp_mov<0xB1>(v[r]);
        v[r] = fmaf(v[r], sg1, t);
    }
    // ---- lane xor 2: DPP quad_perm [2,3,0,1] ----
    #pragma unroll
    for (int r = 0; r < 16; ++r) {
        float t = dpp_mov<0x4E>(v[r]);
        v[r] = fmaf(v[r], sg2, t);
    }
    // ---- lane xor 4: ds_swizzle BitMode xor=4 ----
    #pragma unroll
    for (int r = 0; r < 16; ++r) {
        float t = i2f(__builtin_amdgcn_ds_swizzle(f2i(v[r]), 0x101F));
        v[r] = fmaf(v[r], sg4, t);
    }
    // ---- lane xor 8: DPP row_ror:8 ((l±8)%16 == l^8) ----
    #pragma unroll
    for (int r = 0; r < 16; ++r) {
        float t = dpp_mov<0x128>(v[r]);
        v[r] = fmaf(v[r], sg8, t);
    }
    // ---- lane xor 16: permlane16_swap pair trick (VALU) ----
    #pragma unroll
    for (int r = 0; r < 16; r += 2) {
        iv2 p = __builtin_amdgcn_permlane16_swap(f2i(v[r]), f2i(v[r+1]), false, false);
        float a = i2f(p[0]), b = i2f(p[1]);
        float s = a + b, d = a - b;
        iv2 q = __builtin_amdgcn_permlane16_swap(f2i(s), f2i(d), false, false);
        v[r]   = i2f(q[0]);
        v[r+1] = i2f(q[1]);
    }
    // ---- lane xor 32: permlane32_swap pair trick (VALU) ----
    #pragma unroll
    for (int r = 0; r < 16; r += 2) {
        iv2 p = __builtin_amdgcn_permlane32_swap(f2i(v[r]), f2i(v[r+1]), false, false);
        float a = i2f(p[0]), b = i2f(p[1]);
        float s = a + b, d = a - b;
        iv2 q = __builtin_amdgcn_permlane32_swap(f2i(s), f2i(d), false, false);
        v[r]   = i2f(q[0]);
        v[r+1] = i2f(q[1]);
    }
}

// Precompute g_tilde = g_mu + softplus(g_rho)*eps into workspace (4096 f32).
__global__ __launch_bounds__(256) void whvi_prep(
    const float* __restrict__ g_mu, const float* __restrict__ g_rho,
    const float* __restrict__ eps, float* __restrict__ gt)
{
    const int i = blockIdx.x * 256 + threadIdx.x;
    const float r  = g_rho[i];
    const float sp = fmaxf(r, 0.0f) + log1pf(expf(-fabsf(r)));
    gt[i] = fmaf(sp, eps[i], g_mu[i]);
}

// R8 structure, repeated REPS times (idempotent; same output) so the kernel
// rises above the harness fill dispatches in the rocprof top-5 and we get
// direct VALUBusy / Occupancy / FETCH / WRITE for the real loop body.
template<bool USE_WS>
__global__ __launch_bounds__(256, 8) void whvi_main(
    const float* __restrict__ x,
    const float* __restrict__ s1,
    const float* __restrict__ s2,
    const float* __restrict__ g_mu,
    const float* __restrict__ g_rho,
    const float* __restrict__ eps,
    const float* __restrict__ gt,
    float* __restrict__ out)
{
    const int lane  = threadIdx.x & 63;
    const int stack = blockIdx.y;
    const int row   = (blockIdx.x << 2) + (threadIdx.x >> 6);

    const float sg1 = (lane & 1) ? -1.0f : 1.0f;
    const float sg2 = (lane & 2) ? -1.0f : 1.0f;
    const float sg4 = (lane & 4) ? -1.0f : 1.0f;
    const float sg8 = (lane & 8) ? -1.0f : 1.0f;

    const int pb = stack * D_IN + (lane << 2);
    const float* __restrict__ xr = x + (size_t)row * D_IN;

    #pragma unroll 1
    for (int rep = 0; rep < REPS; ++rep) {
        // compiler barrier: forbid load CSE across reps (keeps reps honest)
        asm volatile("" ::: "memory");

        // ---- load x and s2, fuse the multiply (s2 regs die immediately) ----
        float v[16];
        #pragma unroll
        for (int k = 0; k < 4; ++k) {
            fv4 xt = *(const fv4*)(xr + (k << 8) + (lane << 2));
            fv4 st = *(const fv4*)(s2 + pb + (k << 8));
            v[k*4+0] = xt.x * st.x;
            v[k*4+1] = xt.y * st.y;
            v[k*4+2] = xt.z * st.z;
            v[k*4+3] = xt.w * st.w;
        }

        // ---- issue gt loads now; first use is after FWHT#1 ----
        float gv[16];
        #pragma unroll
        for (int k = 0; k < 4; ++k) {
            if (USE_WS) {
                fv4 tg = *(const fv4*)(gt + pb + (k << 8));
                gv[k*4+0] = tg.x; gv[k*4+1] = tg.y; gv[k*4+2] = tg.z; gv[k*4+3] = tg.w;
            } else {
                #pragma unroll
                for (int c = 0; c < 4; ++c) {
                    const int i = pb + (k << 8) + c;
                    const float rr = g_rho[i];
                    const float sp = fmaxf(rr, 0.0f) + log1pf(expf(-fabsf(rr)));
                    gv[k*4+c] = fmaf(sp, eps[i], g_mu[i]);
                }
            }
        }

        fwht1024(v, sg1, sg2, sg4, sg8);

        #pragma unroll
        for (int r = 0; r < 16; ++r) v[r] *= gv[r];

        // ---- issue s1 loads now; first use is after FWHT#2 ----
        float s1v[16];
        #pragma unroll
        for (int k = 0; k < 4; ++k) {
            fv4 t1 = *(const fv4*)(s1 + pb + (k << 8));
            s1v[k*4+0] = t1.x; s1v[k*4+1] = t1.y; s1v[k*4+2] = t1.z; s1v[k*4+3] = t1.w;
        }

        fwht1024(v, sg1, sg2, sg4, sg8);

        float* __restrict__ orow = out + (size_t)row * OUTW + stack * D_IN;
        #pragma unroll
        for (int k = 0; k < 4; ++k) {
            fv4 t;
            t.x = v[k*4+0] * s1v[k*4+0];
            t.y = v[k*4+1] * s1v[k*4+1];
            t.z = v[k*4+2] * s1v[k*4+2];
            t.w = v[k*4+3] * s1v[k*4+3];
            *(fv4*)(orow + (k << 8) + (lane << 2)) = t;
        }
    }
}

extern "C" void kernel_launch(void* const* d_in, const int* in_sizes, int n_in,
                              void* d_out, int out_size, void* d_ws, size_t ws_size,
                              hipStream_t stream) {
    const float* x     = (const float*)d_in[0];
    const float* s1    = (const float*)d_in[1];
    const float* s2    = (const float*)d_in[2];
    const float* g_mu  = (const float*)d_in[3];
    const float* g_rho = (const float*)d_in[4];
    const float* eps   = (const float*)d_in[5];
    float* out = (float*)d_out;

    // wave = (row, stack): grid (BATCHN/4, STACKN), 4 waves/block.
    dim3 grid(BATCHN / 4, STACKN);

    const bool use_ws = ws_size >= (size_t)(STACKN * D_IN * sizeof(float));
    if (use_ws) {
        float* gt = (float*)d_ws;
        whvi_prep<<<STACKN * D_IN / 256, 256, 0, stream>>>(g_mu, g_rho, eps, gt);
        whvi_main<true><<<grid, 256, 0, stream>>>(x, s1, s2, g_mu, g_rho, eps, gt, out);
    } else {
        whvi_main<false><<<grid, 256, 0, stream>>>(x, s1, s2, g_mu, g_rho, eps, nullptr, out);
    }
}